// Round 10
// baseline (184.033 us; speedup 1.0000x reference)
//
#include <hip/hip_runtime.h>

#define NN 100000
#define EE 1600000
#define DIN 128
#define DOUT 64
#define NH 4

typedef __attribute__((ext_vector_type(8))) short bf16x8;
typedef __attribute__((ext_vector_type(4))) float f32x4;

__device__ __forceinline__ float elu_f(float x) {
  return x > 0.f ? x : (__expf(x) - 1.f);
}
__device__ __forceinline__ float b2f(unsigned short u) {
  union { unsigned int i; float f; } v; v.i = ((unsigned int)u) << 16; return v.f;
}
__device__ __forceinline__ unsigned short f2b(float f) {
  union { float f; unsigned int i; } v; v.f = f;
  unsigned int r = v.i + 0x7fffu + ((v.i >> 16) & 1u);
  return (unsigned short)(r >> 16);
}

// Kernel 1 (prep): W fp32 -> WbfT [H*DOUT][DIN] bf16, and CSR row_ptr via
// binary search over sorted edge_row.
__global__ __launch_bounds__(256) void prep_k(
    const float* __restrict__ W, unsigned short* __restrict__ wbt,
    const int* __restrict__ erow, int* __restrict__ rp) {
  const int gid = blockIdx.x * 256 + threadIdx.x;
  if (gid < NH * DIN * DOUT) {
    int col = gid >> 7, k = gid & 127;  // col = h*64+j
    int h = col >> 6, j = col & 63;
    wbt[gid] = f2b(W[(size_t)h * DIN * DOUT + k * DOUT + j]);
  }
  if (gid <= NN) {
    int lo = 0, hi = EE;
    while (lo < hi) {
      int mid = (lo + hi) >> 1;
      if (erow[mid] < gid) lo = mid + 1; else hi = mid;
    }
    rp[gid] = lo;
  }
}

// Kernel 2 (MFMA): block = 256 threads / 4 waves (wave = head), owns TWO
// 64-row tiles with double-buffered 16 KB LDS. Pipeline: stage tile0->LDS,
// issue tile1 global loads into regs, compute tile0, dump regs->buf1
// (HBM latency hidden under tile0 compute), epilogue tile0 (its barriers
// publish buf1), compute tile1. Operands SWAPPED (W='a') -> lane holds 4
// contiguous xh cols; xh written full-line via LDS-routed epilogue.
__global__ __launch_bounds__(256) void proj_mfma_k(
    const float* __restrict__ inp, const unsigned short* __restrict__ wbt,
    const float* __restrict__ a1, const float* __restrict__ a2,
    float* __restrict__ f1p, float* __restrict__ f2p,
    unsigned short* __restrict__ xh) {
  __shared__ unsigned short lds_a[2][64 * 128];  // 2 x 16 KB, swizzled
  const int tid = threadIdx.x;
  const int h = tid >> 6;   // wave = head
  const int l = tid & 63;
  const int lr = l & 15;
  const int lk = l >> 4;
  const int base = blockIdx.x * 128;

  // --- stage tile0 -> lds_a[0]: fp32 -> bf16, swizzle byte^=(row&7)<<4 ---
  #pragma unroll
  for (int i = 0; i < 8; ++i) {
    const int idx = i * 256 + tid;       // float4 index, 2048 total
    const int row = idx >> 5;            // 0..63
    const int c4 = idx & 31;             // float4 chunk within row
    int grow = base + row;
    if (grow >= NN) grow = NN - 1;
    const float4 v = *(const float4*)(inp + (size_t)grow * DIN + c4 * 4);
    ushort4 w;
    w.x = f2b(v.x); w.y = f2b(v.y); w.z = f2b(v.z); w.w = f2b(v.w);
    const int byte_off = row * 256 + ((c4 * 8) ^ ((row & 7) << 4));
    *(ushort4*)((char*)lds_a[0] + byte_off) = w;
  }
  // --- issue tile1 prefetch into regs (consumed after tile0 compute) ---
  f32x4 pf[8];
  #pragma unroll
  for (int i = 0; i < 8; ++i) {
    const int idx = i * 256 + tid;
    const int row = idx >> 5;
    const int c4 = idx & 31;
    int grow = base + 64 + row;
    if (grow >= NN) grow = NN - 1;
    pf[i] = *(const f32x4*)(inp + (size_t)grow * DIN + c4 * 4);
  }
  __syncthreads();

  float4 a1q[4], a2q[4];
  #pragma unroll
  for (int n = 0; n < 4; ++n) {
    a1q[n] = *(const float4*)(a1 + h * DOUT + n * 16 + lk * 4);
    a2q[n] = *(const float4*)(a2 + h * DOUT + n * 16 + lk * 4);
  }

  #pragma unroll
  for (int t = 0; t < 2; ++t) {
    unsigned short* buf = lds_a[t];
    const int row0 = base + t * 64;

    f32x4 acc[4][4];
    #pragma unroll
    for (int m = 0; m < 4; ++m)
      #pragma unroll
      for (int n = 0; n < 4; ++n)
        acc[m][n] = (f32x4)(0.f);

    #pragma unroll
    for (int kc = 0; kc < 4; ++kc) {
      bf16x8 bfn[4];
      #pragma unroll
      for (int n = 0; n < 4; ++n)
        bfn[n] = *(const bf16x8*)(wbt + (size_t)(h * DOUT + n * 16 + lr) * DIN +
                                  kc * 32 + lk * 8);
      #pragma unroll
      for (int m = 0; m < 4; ++m) {
        const int r = m * 16 + lr;
        const bf16x8 af = *(const bf16x8*)((char*)buf + r * 256 +
                                           ((kc * 64 + lk * 16) ^ ((r & 7) << 4)));
        #pragma unroll
        for (int n = 0; n < 4; ++n)
          acc[m][n] = __builtin_amdgcn_mfma_f32_16x16x32_bf16(
              bfn[n], af, acc[m][n], 0, 0, 0);
      }
    }

    // attention-logit partials from fp32 acc
    float p1m[4], p2m[4];
    #pragma unroll
    for (int m = 0; m < 4; ++m) {
      float p1 = 0.f, p2 = 0.f;
      #pragma unroll
      for (int n = 0; n < 4; ++n) {
        const f32x4 a = acc[m][n];
        p1 = fmaf(a[0], a1q[n].x, p1); p1 = fmaf(a[1], a1q[n].y, p1);
        p1 = fmaf(a[2], a1q[n].z, p1); p1 = fmaf(a[3], a1q[n].w, p1);
        p2 = fmaf(a[0], a2q[n].x, p2); p2 = fmaf(a[1], a2q[n].y, p2);
        p2 = fmaf(a[2], a2q[n].z, p2); p2 = fmaf(a[3], a2q[n].w, p2);
      }
      p1 += __shfl_xor(p1, 16); p1 += __shfl_xor(p1, 32);
      p2 += __shfl_xor(p2, 16); p2 += __shfl_xor(p2, 32);
      p1m[m] = p1; p2m[m] = p2;
    }

    // dump tile1 prefetch regs -> lds_a[1] (loads have had tile0's whole
    // compute phase to land; epilogue barriers below publish it)
    if (t == 0) {
      #pragma unroll
      for (int i = 0; i < 8; ++i) {
        const int idx = i * 256 + tid;
        const int row = idx >> 5;
        const int c4 = idx & 31;
        ushort4 w;
        w.x = f2b(pf[i][0]); w.y = f2b(pf[i][1]);
        w.z = f2b(pf[i][2]); w.w = f2b(pf[i][3]);
        const int byte_off = row * 256 + ((c4 * 8) ^ ((row & 7) << 4));
        *(ushort4*)((char*)lds_a[1] + byte_off) = w;
      }
    }

    // xh epilogue via buf, two head-half phases, full-line stores
    #pragma unroll
    for (int half = 0; half < 2; ++half) {
      __syncthreads();
      if ((h >> 1) == half) {
        #pragma unroll
        for (int m = 0; m < 4; ++m) {
          const int row = m * 16 + lr;
          #pragma unroll
          for (int n = 0; n < 4; ++n) {
            const f32x4 a = acc[m][n];
            ushort4 pk;
            pk.x = f2b(a[0]); pk.y = f2b(a[1]); pk.z = f2b(a[2]); pk.w = f2b(a[3]);
            const int colb = (h & 1) * 128 + n * 32 + lk * 8;  // byte col
            *(ushort4*)((char*)buf + row * 256 + (colb ^ ((row & 7) << 4))) = pk;
          }
        }
      }
      __syncthreads();
      #pragma unroll
      for (int i = 0; i < 4; ++i) {
        const int idx = i * 256 + tid;       // 1024 f32x4 = 16 KB
        const int row = idx >> 4, c = idx & 15;
        const f32x4 v = *(const f32x4*)((char*)buf + row * 256 +
                                        ((c * 16) ^ ((row & 7) << 4)));
        const int grow = row0 + row;
        if (grow < NN)
          *(f32x4*)((char*)xh + (size_t)grow * 512 + half * 256 + c * 16) = v;
      }
    }

    #pragma unroll
    for (int m = 0; m < 4; ++m) {
      const int row = row0 + m * 16 + lr;
      if (row < NN && lk == 0) {
        f1p[(size_t)row * NH + h] = elu_f(p1m[m]);
        f2p[(size_t)row * NH + h] = elu_f(p2m[m]);
      }
    }
    __syncthreads();  // buf free for next iteration's reads
  }
}

// Kernel 3: one wave per destination row, all 4 heads at once (R5 winner).
// 16-lane group g = head g. 8-deep pipelined edge loop; tail via masked
// 8-batch. Stream-once ecol/eval loaded nontemporal to spare L2 for xh.
__global__ __launch_bounds__(256) void agg_k(
    const int* __restrict__ rp, const int* __restrict__ ecol,
    const float* __restrict__ eval, const float* __restrict__ f1p,
    const float* __restrict__ f2p, const unsigned short* __restrict__ xh,
    const float* __restrict__ b, float* __restrict__ out) {
  const int tid = threadIdx.x;
  const int wave = tid >> 6, lane = tid & 63;
  const int r = blockIdx.x * 4 + wave;
  if (r >= NN) return;
  const int g = lane >> 4;  // head index for this lane group
  const int e0 = __builtin_amdgcn_readfirstlane(rp[r]);
  const int e1 = __builtin_amdgcn_readfirstlane(rp[r + 1]);
  const float f1r = f1p[(size_t)r * NH + g];
  float ax = 0.f, ay = 0.f, az = 0.f, aw = 0.f;
  float ssum = 0.f;
  int e = e0;
  for (; e + 8 <= e1; e += 8) {
    int c[8]; float vv[8];
    #pragma unroll
    for (int u = 0; u < 8; ++u) {
      c[u] = __builtin_nontemporal_load(ecol + e + u);
      vv[u] = __builtin_nontemporal_load(eval + e + u);
    }
    ushort4 xv[8]; float f2v[8];
    #pragma unroll
    for (int u = 0; u < 8; ++u) {
      xv[u] = *(const ushort4*)(xh + (size_t)c[u] * (NH * DOUT) + lane * 4);
      f2v[u] = f2p[(size_t)c[u] * NH + g];
    }
    #pragma unroll
    for (int u = 0; u < 8; ++u) {
      const float t = vv[u] * (f1r + f2v[u]);
      const float ex = __expf(fmaxf(t, 0.2f * t));
      ssum += ex;
      ax = fmaf(ex, b2f(xv[u].x), ax);
      ay = fmaf(ex, b2f(xv[u].y), ay);
      az = fmaf(ex, b2f(xv[u].z), az);
      aw = fmaf(ex, b2f(xv[u].w), aw);
    }
  }
  if (e < e1) {
    int c[8]; float vv[8]; bool okk[8];
    #pragma unroll
    for (int u = 0; u < 8; ++u) {
      int ee = e + u;
      okk[u] = ee < e1;
      if (!okk[u]) ee = e1 - 1;
      c[u] = ecol[ee]; vv[u] = eval[ee];
    }
    ushort4 xv[8]; float f2v[8];
    #pragma unroll
    for (int u = 0; u < 8; ++u) {
      xv[u] = *(const ushort4*)(xh + (size_t)c[u] * (NH * DOUT) + lane * 4);
      f2v[u] = f2p[(size_t)c[u] * NH + g];
    }
    #pragma unroll
    for (int u = 0; u < 8; ++u) {
      const float t = vv[u] * (f1r + f2v[u]);
      float ex = __expf(fmaxf(t, 0.2f * t));
      ex = okk[u] ? ex : 0.f;
      ssum += ex;
      ax = fmaf(ex, b2f(xv[u].x), ax);
      ay = fmaf(ex, b2f(xv[u].y), ay);
      az = fmaf(ex, b2f(xv[u].z), az);
      aw = fmaf(ex, b2f(xv[u].w), aw);
    }
  }
  const float4 bb = *(const float4*)(b + lane * 4);  // b flattened [H*64]
  const float inv = (e1 > e0) ? (1.f / ssum) : 0.f;
  float v0 = elu_f(ax * inv + bb.x);
  float v1 = elu_f(ay * inv + bb.y);
  float v2 = elu_f(az * inv + bb.z);
  float v3 = elu_f(aw * inv + bb.w);
  // mean over heads: lanes {l, l^16, l^32, l^48} hold same dim, different head
  v0 += __shfl_xor(v0, 16); v1 += __shfl_xor(v1, 16);
  v2 += __shfl_xor(v2, 16); v3 += __shfl_xor(v3, 16);
  v0 += __shfl_xor(v0, 32); v1 += __shfl_xor(v1, 32);
  v2 += __shfl_xor(v2, 32); v3 += __shfl_xor(v3, 32);
  if (lane < 16) {
    f32x4 o = {v0 * 0.25f, v1 * 0.25f, v2 * 0.25f, v3 * 0.25f};
    __builtin_nontemporal_store(o, (f32x4*)(out + (size_t)r * DOUT + lane * 4));
  }
}

extern "C" void kernel_launch(void* const* d_in, const int* in_sizes, int n_in,
                              void* d_out, int out_size, void* d_ws, size_t ws_size,
                              hipStream_t stream) {
  const float* inp = (const float*)d_in[0];
  const float* W   = (const float*)d_in[1];
  const float* a1  = (const float*)d_in[2];
  const float* a2  = (const float*)d_in[3];
  const float* b   = (const float*)d_in[4];
  const float* ev  = (const float*)d_in[5];
  const int* erow  = (const int*)d_in[6];
  const int* ecol  = (const int*)d_in[7];
  float* out = (float*)d_out;

  char* ws = (char*)d_ws;
  size_t off = 0;
  int* rp = (int*)(ws + off);
  off += (((size_t)(NN + 1) * 4) + 255) & ~(size_t)255;
  float* f1p = (float*)(ws + off);
  off += (((size_t)NH * NN * 4) + 255) & ~(size_t)255;
  float* f2p = (float*)(ws + off);
  off += (((size_t)NH * NN * 4) + 255) & ~(size_t)255;
  unsigned short* xh = (unsigned short*)(ws + off);
  off += (((size_t)NN * NH * DOUT * 2) + 255) & ~(size_t)255;
  unsigned short* wbt = (unsigned short*)(ws + off);

  prep_k<<<(NN + 1 + 255) / 256, 256, 0, stream>>>(W, wbt, erow, rp);
  proj_mfma_k<<<(NN + 127) / 128, 256, 0, stream>>>(inp, wbt, a1, a2, f1p, f2p, xh);
  agg_k<<<(NN + 3) / 4, 256, 0, stream>>>(rp, ecol, ev, f1p, f2p, xh, b, out);
}

// Round 11
// 171.785 us; speedup vs baseline: 1.0713x; 1.0713x over previous
//
#include <hip/hip_runtime.h>

#define NN 100000
#define EE 1600000
#define DIN 128
#define DOUT 64
#define NH 4

typedef __attribute__((ext_vector_type(8))) short bf16x8;
typedef __attribute__((ext_vector_type(4))) float f32x4;

__device__ __forceinline__ float elu_f(float x) {
  return x > 0.f ? x : (__expf(x) - 1.f);
}
__device__ __forceinline__ float b2f(unsigned short u) {
  union { unsigned int i; float f; } v; v.i = ((unsigned int)u) << 16; return v.f;
}
__device__ __forceinline__ unsigned short f2b(float f) {
  union { float f; unsigned int i; } v; v.f = f;
  unsigned int r = v.i + 0x7fffu + ((v.i >> 16) & 1u);
  return (unsigned short)(r >> 16);
}

// Kernel 1 (prep): W fp32 -> WbfT [H*DOUT][DIN] bf16, and CSR row_ptr via
// binary search over sorted edge_row.
__global__ __launch_bounds__(256) void prep_k(
    const float* __restrict__ W, unsigned short* __restrict__ wbt,
    const int* __restrict__ erow, int* __restrict__ rp) {
  const int gid = blockIdx.x * 256 + threadIdx.x;
  if (gid < NH * DIN * DOUT) {
    int col = gid >> 7, k = gid & 127;  // col = h*64+j
    int h = col >> 6, j = col & 63;
    wbt[gid] = f2b(W[(size_t)h * DIN * DOUT + k * DOUT + j]);
  }
  if (gid <= NN) {
    int lo = 0, hi = EE;
    while (lo < hi) {
      int mid = (lo + hi) >> 1;
      if (erow[mid] < gid) lo = mid + 1; else hi = mid;
    }
    rp[gid] = lo;
  }
}

// Kernel 2 (MFMA): block = 64 rows x 256 cols, 4 waves = 4 heads.
// A staged once into LDS as bf16 (XOR-swizzled), shared by the 4 waves.
// Operands SWAPPED (W='a', input='b') -> lane holds 4 contiguous xh cols.
// Epilogue routes D-frags through the same 16 KB LDS (two head-half
// phases) so xh global stores are full-line 256 B segments.
__global__ __launch_bounds__(256) void proj_mfma_k(
    const float* __restrict__ inp, const unsigned short* __restrict__ wbt,
    const float* __restrict__ a1, const float* __restrict__ a2,
    float* __restrict__ f1p, float* __restrict__ f2p,
    unsigned short* __restrict__ xh) {
  __shared__ unsigned short lds_a[64 * 128];  // 16 KB: A-tile, then xh buffer
  const int tid = threadIdx.x;
  const int h = tid >> 6;   // wave = head
  const int l = tid & 63;
  const int lr = l & 15;
  const int lk = l >> 4;
  const int row0 = blockIdx.x * 64;

  // --- stage A: 64 rows x 128 k, fp32 -> bf16, swizzle byte^=(row&7)<<4 ---
  #pragma unroll
  for (int i = 0; i < 8; ++i) {
    const int idx = i * 256 + tid;       // float4 index, 2048 total
    const int row = idx >> 5;            // 0..63
    const int c4 = idx & 31;             // float4 chunk within row
    int grow = row0 + row;
    if (grow >= NN) grow = NN - 1;
    const float4 v = *(const float4*)(inp + (size_t)grow * DIN + c4 * 4);
    ushort4 w;
    w.x = f2b(v.x); w.y = f2b(v.y); w.z = f2b(v.z); w.w = f2b(v.w);
    const int byte_off = row * 256 + ((c4 * 8) ^ ((row & 7) << 4));
    *(ushort4*)((char*)lds_a + byte_off) = w;
  }
  __syncthreads();

  f32x4 acc[4][4];
  #pragma unroll
  for (int m = 0; m < 4; ++m)
    #pragma unroll
    for (int n = 0; n < 4; ++n)
      acc[m][n] = (f32x4)(0.f);

  #pragma unroll
  for (int kc = 0; kc < 4; ++kc) {
    bf16x8 bfn[4];
    #pragma unroll
    for (int n = 0; n < 4; ++n)
      bfn[n] = *(const bf16x8*)(wbt + (size_t)(h * DOUT + n * 16 + lr) * DIN +
                                kc * 32 + lk * 8);
    #pragma unroll
    for (int m = 0; m < 4; ++m) {
      const int r = m * 16 + lr;
      const bf16x8 af = *(const bf16x8*)((char*)lds_a + r * 256 +
                                         ((kc * 64 + lk * 16) ^ ((r & 7) << 4)));
      #pragma unroll
      for (int n = 0; n < 4; ++n)
        acc[m][n] = __builtin_amdgcn_mfma_f32_16x16x32_bf16(
            bfn[n], af, acc[m][n], 0, 0, 0);
    }
  }

  // --- attention-logit partials from fp32 acc (before LDS reuse) ---
  float4 a1q[4], a2q[4];
  #pragma unroll
  for (int n = 0; n < 4; ++n) {
    a1q[n] = *(const float4*)(a1 + h * DOUT + n * 16 + lk * 4);
    a2q[n] = *(const float4*)(a2 + h * DOUT + n * 16 + lk * 4);
  }
  float p1m[4], p2m[4];
  #pragma unroll
  for (int m = 0; m < 4; ++m) {
    float p1 = 0.f, p2 = 0.f;
    #pragma unroll
    for (int n = 0; n < 4; ++n) {
      const f32x4 a = acc[m][n];
      p1 = fmaf(a[0], a1q[n].x, p1); p1 = fmaf(a[1], a1q[n].y, p1);
      p1 = fmaf(a[2], a1q[n].z, p1); p1 = fmaf(a[3], a1q[n].w, p1);
      p2 = fmaf(a[0], a2q[n].x, p2); p2 = fmaf(a[1], a2q[n].y, p2);
      p2 = fmaf(a[2], a2q[n].z, p2); p2 = fmaf(a[3], a2q[n].w, p2);
    }
    p1 += __shfl_xor(p1, 16); p1 += __shfl_xor(p1, 32);
    p2 += __shfl_xor(p2, 16); p2 += __shfl_xor(p2, 32);
    p1m[m] = p1; p2m[m] = p2;
  }

  // --- xh epilogue via LDS, two head-half phases, full-line stores ---
  #pragma unroll
  for (int half = 0; half < 2; ++half) {
    __syncthreads();
    if ((h >> 1) == half) {
      #pragma unroll
      for (int m = 0; m < 4; ++m) {
        const int row = m * 16 + lr;
        #pragma unroll
        for (int n = 0; n < 4; ++n) {
          const f32x4 a = acc[m][n];
          ushort4 pk;
          pk.x = f2b(a[0]); pk.y = f2b(a[1]); pk.z = f2b(a[2]); pk.w = f2b(a[3]);
          const int colb = (h & 1) * 128 + n * 32 + lk * 8;  // byte col 0..255
          *(ushort4*)((char*)lds_a + row * 256 + (colb ^ ((row & 7) << 4))) = pk;
        }
      }
    }
    __syncthreads();
    #pragma unroll
    for (int i = 0; i < 4; ++i) {
      const int idx = i * 256 + tid;       // 1024 f32x4 = 16 KB
      const int row = idx >> 4, c = idx & 15;
      const f32x4 v = *(const f32x4*)((char*)lds_a + row * 256 +
                                      ((c * 16) ^ ((row & 7) << 4)));
      const int grow = row0 + row;
      if (grow < NN)
        *(f32x4*)((char*)xh + (size_t)grow * 512 + half * 256 + c * 16) = v;
    }
  }

  #pragma unroll
  for (int m = 0; m < 4; ++m) {
    const int row = row0 + m * 16 + lr;
    if (row < NN && lk == 0) {
      f1p[(size_t)row * NH + h] = elu_f(p1m[m]);
      f2p[(size_t)row * NH + h] = elu_f(p2m[m]);
    }
  }
}

// Kernel 3: one wave per destination row, all 4 heads at once (R5 winner).
// 16-lane group g = head g. 8-deep pipelined edge loop; tail via masked
// 8-batch. Stream-once ecol/eval loaded nontemporal to spare L2 for xh.
__global__ __launch_bounds__(256) void agg_k(
    const int* __restrict__ rp, const int* __restrict__ ecol,
    const float* __restrict__ eval, const float* __restrict__ f1p,
    const float* __restrict__ f2p, const unsigned short* __restrict__ xh,
    const float* __restrict__ b, float* __restrict__ out) {
  const int tid = threadIdx.x;
  const int wave = tid >> 6, lane = tid & 63;
  const int r = blockIdx.x * 4 + wave;
  if (r >= NN) return;
  const int g = lane >> 4;  // head index for this lane group
  const int e0 = __builtin_amdgcn_readfirstlane(rp[r]);
  const int e1 = __builtin_amdgcn_readfirstlane(rp[r + 1]);
  const float f1r = f1p[(size_t)r * NH + g];
  float ax = 0.f, ay = 0.f, az = 0.f, aw = 0.f;
  float ssum = 0.f;
  int e = e0;
  for (; e + 8 <= e1; e += 8) {
    int c[8]; float vv[8];
    #pragma unroll
    for (int u = 0; u < 8; ++u) {
      c[u] = __builtin_nontemporal_load(ecol + e + u);
      vv[u] = __builtin_nontemporal_load(eval + e + u);
    }
    ushort4 xv[8]; float f2v[8];
    #pragma unroll
    for (int u = 0; u < 8; ++u) {
      xv[u] = *(const ushort4*)(xh + (size_t)c[u] * (NH * DOUT) + lane * 4);
      f2v[u] = f2p[(size_t)c[u] * NH + g];
    }
    #pragma unroll
    for (int u = 0; u < 8; ++u) {
      const float t = vv[u] * (f1r + f2v[u]);
      const float ex = __expf(fmaxf(t, 0.2f * t));
      ssum += ex;
      ax = fmaf(ex, b2f(xv[u].x), ax);
      ay = fmaf(ex, b2f(xv[u].y), ay);
      az = fmaf(ex, b2f(xv[u].z), az);
      aw = fmaf(ex, b2f(xv[u].w), aw);
    }
  }
  if (e < e1) {
    int c[8]; float vv[8]; bool okk[8];
    #pragma unroll
    for (int u = 0; u < 8; ++u) {
      int ee = e + u;
      okk[u] = ee < e1;
      if (!okk[u]) ee = e1 - 1;
      c[u] = ecol[ee]; vv[u] = eval[ee];
    }
    ushort4 xv[8]; float f2v[8];
    #pragma unroll
    for (int u = 0; u < 8; ++u) {
      xv[u] = *(const ushort4*)(xh + (size_t)c[u] * (NH * DOUT) + lane * 4);
      f2v[u] = f2p[(size_t)c[u] * NH + g];
    }
    #pragma unroll
    for (int u = 0; u < 8; ++u) {
      const float t = vv[u] * (f1r + f2v[u]);
      float ex = __expf(fmaxf(t, 0.2f * t));
      ex = okk[u] ? ex : 0.f;
      ssum += ex;
      ax = fmaf(ex, b2f(xv[u].x), ax);
      ay = fmaf(ex, b2f(xv[u].y), ay);
      az = fmaf(ex, b2f(xv[u].z), az);
      aw = fmaf(ex, b2f(xv[u].w), aw);
    }
  }
  const float4 bb = *(const float4*)(b + lane * 4);  // b flattened [H*64]
  const float inv = (e1 > e0) ? (1.f / ssum) : 0.f;
  float v0 = elu_f(ax * inv + bb.x);
  float v1 = elu_f(ay * inv + bb.y);
  float v2 = elu_f(az * inv + bb.z);
  float v3 = elu_f(aw * inv + bb.w);
  // mean over heads: lanes {l, l^16, l^32, l^48} hold same dim, different head
  v0 += __shfl_xor(v0, 16); v1 += __shfl_xor(v1, 16);
  v2 += __shfl_xor(v2, 16); v3 += __shfl_xor(v3, 16);
  v0 += __shfl_xor(v0, 32); v1 += __shfl_xor(v1, 32);
  v2 += __shfl_xor(v2, 32); v3 += __shfl_xor(v3, 32);
  if (lane < 16) {
    f32x4 o = {v0 * 0.25f, v1 * 0.25f, v2 * 0.25f, v3 * 0.25f};
    __builtin_nontemporal_store(o, (f32x4*)(out + (size_t)r * DOUT + lane * 4));
  }
}

extern "C" void kernel_launch(void* const* d_in, const int* in_sizes, int n_in,
                              void* d_out, int out_size, void* d_ws, size_t ws_size,
                              hipStream_t stream) {
  const float* inp = (const float*)d_in[0];
  const float* W   = (const float*)d_in[1];
  const float* a1  = (const float*)d_in[2];
  const float* a2  = (const float*)d_in[3];
  const float* b   = (const float*)d_in[4];
  const float* ev  = (const float*)d_in[5];
  const int* erow  = (const int*)d_in[6];
  const int* ecol  = (const int*)d_in[7];
  float* out = (float*)d_out;

  char* ws = (char*)d_ws;
  size_t off = 0;
  int* rp = (int*)(ws + off);
  off += (((size_t)(NN + 1) * 4) + 255) & ~(size_t)255;
  float* f1p = (float*)(ws + off);
  off += (((size_t)NH * NN * 4) + 255) & ~(size_t)255;
  float* f2p = (float*)(ws + off);
  off += (((size_t)NH * NN * 4) + 255) & ~(size_t)255;
  unsigned short* xh = (unsigned short*)(ws + off);
  off += (((size_t)NN * NH * DOUT * 2) + 255) & ~(size_t)255;
  unsigned short* wbt = (unsigned short*)(ws + off);

  prep_k<<<(NN + 1 + 255) / 256, 256, 0, stream>>>(W, wbt, erow, rp);
  proj_mfma_k<<<(NN + 63) / 64, 256, 0, stream>>>(inp, wbt, a1, a2, f1p, f2p, xh);
  agg_k<<<(NN + 3) / 4, 256, 0, stream>>>(rp, ecol, ev, f1p, f2p, xh, b, out);
}